// Round 9
// baseline (264.226 us; speedup 1.0000x reference)
//
#include <hip/hip_runtime.h>
#include <stdint.h>

#define EMBED 768
#define HD 64
#define SEQ 4096
#define BATCH 4
#define NROW (BATCH * SEQ)   // 16384
#define NBAND (NROW / 64)    // 256 bands of 64 query rows
#define KSPLIT 8

typedef __bf16 bf16x8 __attribute__((ext_vector_type(8)));
typedef __bf16 bf16x4 __attribute__((ext_vector_type(4)));
typedef float f32x4 __attribute__((ext_vector_type(4)));

// ---------------- W -> wT [192][768] bf16 (once, tiny) ----------------
__global__ __launch_bounds__(256)
void wconv_kernel(const float* __restrict__ Wq, const float* __restrict__ Wk,
                  const float* __restrict__ Wv, __bf16* __restrict__ wT) {
    int id = blockIdx.x * 256 + threadIdx.x;   // < 192*768
    int c = id / EMBED, k = id - c * EMBED;
    const float* W = (c < 64) ? Wq : (c < 128) ? Wk : Wv;
    wT[id] = (__bf16)W[(size_t)k * HD + (c & 63)];
}

// ---------------- fused QKV GEMM (UNCHANGED from R8 for attribution) ----------------
__global__ __launch_bounds__(256, 4)
void qkv_gemm_kernel(const float* __restrict__ hidden, const __bf16* __restrict__ wT,
                     const float* __restrict__ bq, const float* __restrict__ bk,
                     const float* __restrict__ bv,
                     __bf16* __restrict__ qo, __bf16* __restrict__ ko,
                     __bf16* __restrict__ vto) {
    const int m0 = blockIdx.x * 16;
    const int w  = threadIdx.x >> 6;
    const int lane = threadIdx.x & 63, lr = lane & 15, lg = lane >> 4;

    f32x4 acc[3];
    #pragma unroll
    for (int j = 0; j < 3; ++j) acc[j] = (f32x4){0.f, 0.f, 0.f, 0.f};

    const float* hrow = hidden + (size_t)(m0 + lr) * EMBED + lg * 8;

    float4 c00 = *(const float4*)(hrow + 0);
    float4 c01 = *(const float4*)(hrow + 4);
    float4 c10 = *(const float4*)(hrow + 32);
    float4 c11 = *(const float4*)(hrow + 36);

    for (int k0 = 0; k0 < EMBED; k0 += 64) {
        const float* pf = hrow + ((k0 + 64 < EMBED) ? (k0 + 64) : k0);
        float4 n00 = *(const float4*)(pf + 0);
        float4 n01 = *(const float4*)(pf + 4);
        float4 n10 = *(const float4*)(pf + 32);
        float4 n11 = *(const float4*)(pf + 36);

        bf16x8 a0, a1;
        a0[0] = (__bf16)c00.x; a0[1] = (__bf16)c00.y; a0[2] = (__bf16)c00.z; a0[3] = (__bf16)c00.w;
        a0[4] = (__bf16)c01.x; a0[5] = (__bf16)c01.y; a0[6] = (__bf16)c01.z; a0[7] = (__bf16)c01.w;
        a1[0] = (__bf16)c10.x; a1[1] = (__bf16)c10.y; a1[2] = (__bf16)c10.z; a1[3] = (__bf16)c10.w;
        a1[4] = (__bf16)c11.x; a1[5] = (__bf16)c11.y; a1[6] = (__bf16)c11.z; a1[7] = (__bf16)c11.w;

        #pragma unroll
        for (int j = 0; j < 3; ++j) {
            const int col = w * 48 + j * 16 + lr;       // 0..191
            bf16x8 b0 = *(const bf16x8*)(wT + (size_t)col * EMBED + k0 + lg * 8);
            acc[j] = __builtin_amdgcn_mfma_f32_16x16x32_bf16(a0, b0, acc[j], 0, 0, 0);
            bf16x8 b1 = *(const bf16x8*)(wT + (size_t)col * EMBED + k0 + 32 + lg * 8);
            acc[j] = __builtin_amdgcn_mfma_f32_16x16x32_bf16(a1, b1, acc[j], 0, 0, 0);
        }
        c00 = n00; c01 = n01; c10 = n10; c11 = n11;
    }

    const float qsc = 0.18033688011112042f;   // log2(e)/sqrt(64)
    const int row0 = m0 + lg * 4;             // C/D: row=(lane>>4)*4+r, col=lr
    #pragma unroll
    for (int j = 0; j < 3; ++j) {
        const int cw  = w * 48 + j * 16;      // 16-col group lies in ONE matrix
        const int mat = cw >> 6;
        const int cm  = (cw & 63) + lr;
        if (mat == 0) {
            const float bb = bq[cm];
            #pragma unroll
            for (int r = 0; r < 4; ++r)
                qo[(size_t)(row0 + r) * HD + cm] = (__bf16)((acc[j][r] + bb) * qsc);
        } else if (mat == 1) {
            const float bb = bk[cm];
            #pragma unroll
            for (int r = 0; r < 4; ++r)
                ko[(size_t)(row0 + r) * HD + cm] = (__bf16)(acc[j][r] + bb);
        } else {
            const float bb = bv[cm];
            bf16x4 pv;
            pv[0] = (__bf16)(acc[j][0] + bb);
            pv[1] = (__bf16)(acc[j][1] + bb);
            pv[2] = (__bf16)(acc[j][2] + bb);
            pv[3] = (__bf16)(acc[j][3] + bb);
            *(bf16x4*)&vto[(size_t)cm * NROW + row0] = pv;   // V transposed
        }
    }
}

// ---------------- causal flash attention (R4 geometry + (256,8) occupancy) ----------------
// grid: NBAND*KSPLIT = 2048 blocks x 256 thr (4 waves). Block = 64-row band x
// one key split; all 4 waves iterate the SAME key chunk (K/V loads shared via
// L1/L2) with per-wave diagonal trim. Wave = 16 rows. Longest bands first.
// No __syncthreads (per-wave LDS P + lgkmcnt fence; early returns safe).
__global__ __launch_bounds__(256, 8)
void attn_kernel(const __bf16* __restrict__ qg, const __bf16* __restrict__ kg,
                 const __bf16* __restrict__ vtg,
                 float* __restrict__ opart, float* __restrict__ ml) {
    __shared__ __bf16 p_lds[4][16][72];   // per-wave region; 144B stride: 2-way banks

    const int bid = blockIdx.x;
    const int gi  = bid >> 3;            // band index (descending work)
    const int sp  = bid & (KSPLIT - 1);
    const int t   = 63 - (gi >> 2);      // per-batch 64-row band, longest first
    const int b   = gi & 3;
    const int q0b = t * 64;
    const int nkb = q0b + 64;
    const int chunk = ((nkb + 511) >> 9) << 6;   // ceil(nkb/512)*64
    const int kb = sp * chunk;

    const int w    = threadIdx.x >> 6;
    const int lane = threadIdx.x & 63, lr = lane & 15, lg = lane >> 4;
    const int q0 = q0b + w * 16;         // wave's 16 rows
    const int nk = q0 + 16;
    const int ke = (kb + chunk < nk) ? (kb + chunk) : nk;

    float* mlp = ml + ((size_t)gi * KSPLIT + sp) * 128;   // [0..64)=m, [64..128)=l
    const int rb = w * 16 + lg * 4;      // row-in-band base for this thread

    if (kb >= ke) {                      // empty split for this wave: l=0
        if (lr == 0) {
            #pragma unroll
            for (int r = 0; r < 4; ++r) mlp[64 + rb + r] = 0.f;
        }
        return;
    }

    const __bf16* qb = qg  + (size_t)b * SEQ * HD;
    const __bf16* kp = kg  + (size_t)b * SEQ * HD;
    const __bf16* vb = vtg + (size_t)b * SEQ;   // vb[d*NROW + key]

    const bf16x8 qf0 = *(const bf16x8*)&qb[(q0 + lr) * HD + lg * 8];
    const bf16x8 qf1 = *(const bf16x8*)&qb[(q0 + lr) * HD + 32 + lg * 8];

    f32x4 acc[4];
    const f32x4 zero4 = {0.f, 0.f, 0.f, 0.f};
    #pragma unroll
    for (int n = 0; n < 4; ++n) acc[n] = zero4;
    float m[4], lsum[4];
    #pragma unroll
    for (int r = 0; r < 4; ++r) { m[r] = -INFINITY; lsum[r] = 0.f; }

    for (int kb0 = kb; kb0 < ke; kb0 += 64) {
        f32x4 sj[4];   // scores already in exp2 domain (Q pre-scaled)
        #pragma unroll
        for (int j = 0; j < 4; ++j) {
            bf16x8 kf0 = *(const bf16x8*)&kp[(size_t)(kb0 + j * 16 + lr) * HD + lg * 8];
            bf16x8 kf1 = *(const bf16x8*)&kp[(size_t)(kb0 + j * 16 + lr) * HD + 32 + lg * 8];
            f32x4 z = zero4;
            z = __builtin_amdgcn_mfma_f32_16x16x32_bf16(qf0, kf0, z, 0, 0, 0);
            z = __builtin_amdgcn_mfma_f32_16x16x32_bf16(qf1, kf1, z, 0, 0, 0);
            sj[j] = z;
        }

        if (kb0 + 63 > q0) {  // tile crosses this wave's diagonal: causal mask
            #pragma unroll
            for (int j = 0; j < 4; ++j)
                #pragma unroll
                for (int r = 0; r < 4; ++r)
                    if (kb0 + j * 16 + lr > q0 + lg * 4 + r) sj[j][r] = -1e30f;
        }

        float mx[4];
        #pragma unroll
        for (int r = 0; r < 4; ++r)
            mx[r] = fmaxf(fmaxf(sj[0][r], sj[1][r]), fmaxf(sj[2][r], sj[3][r]));
        #pragma unroll
        for (int off = 1; off < 16; off <<= 1)
            #pragma unroll
            for (int r = 0; r < 4; ++r) mx[r] = fmaxf(mx[r], __shfl_xor(mx[r], off));

        float rs[4], so[4];
        #pragma unroll
        for (int r = 0; r < 4; ++r) {
            const float nm = fmaxf(m[r], mx[r]);
            so[r] = __builtin_exp2f(m[r] - nm);   // m=-inf first iter -> 0
            m[r] = nm;
            float a = 0.f;
            #pragma unroll
            for (int j = 0; j < 4; ++j) {
                sj[j][r] = __builtin_exp2f(sj[j][r] - nm);   // P in place
                a += sj[j][r];
            }
            rs[r] = a;
        }
        #pragma unroll
        for (int off = 1; off < 16; off <<= 1)
            #pragma unroll
            for (int r = 0; r < 4; ++r) rs[r] += __shfl_xor(rs[r], off);
        #pragma unroll
        for (int r = 0; r < 4; ++r) lsum[r] = lsum[r] * so[r] + rs[r];
        #pragma unroll
        for (int n = 0; n < 4; ++n)
            #pragma unroll
            for (int r = 0; r < 4; ++r) acc[n][r] *= so[r];

        // P (16x64) -> per-wave LDS bf16, re-read as A-fragments (fence only)
        #pragma unroll
        for (int j = 0; j < 4; ++j)
            #pragma unroll
            for (int r = 0; r < 4; ++r)
                p_lds[w][lg * 4 + r][j * 16 + lr] = (__bf16)sj[j][r];
        asm volatile("s_waitcnt lgkmcnt(0)" ::: "memory");
        const bf16x8 pa0 = *(const bf16x8*)&p_lds[w][lr][lg * 8];
        const bf16x8 pa1 = *(const bf16x8*)&p_lds[w][lr][32 + lg * 8];
        #pragma unroll
        for (int n = 0; n < 4; ++n) {
            bf16x8 vf0 = *(const bf16x8*)&vb[(size_t)(n * 16 + lr) * NROW + kb0 + lg * 8];
            acc[n] = __builtin_amdgcn_mfma_f32_16x16x32_bf16(pa0, vf0, acc[n], 0, 0, 0);
            bf16x8 vf1 = *(const bf16x8*)&vb[(size_t)(n * 16 + lr) * NROW + kb0 + 32 + lg * 8];
            acc[n] = __builtin_amdgcn_mfma_f32_16x16x32_bf16(pa1, vf1, acc[n], 0, 0, 0);
        }
        asm volatile("" ::: "memory");
    }

    // epilogue: unnormalized O partial + per-row m/l
    float* Op = opart + (size_t)(gi * KSPLIT + sp) * (64 * 64);
    #pragma unroll
    for (int n = 0; n < 4; ++n)
        #pragma unroll
        for (int r = 0; r < 4; ++r)
            Op[(size_t)(rb + r) * 64 + n * 16 + lr] = acc[n][r];
    if (lr == 0) {
        #pragma unroll
        for (int r = 0; r < 4; ++r) {
            mlp[rb + r]      = m[r];
            mlp[64 + rb + r] = (m[r] > -1e29f) ? lsum[r] : 0.f;
        }
    }
}

// ---------------- combine split-K partials ----------------
// grid: NROW*HD/256 x 256 thr; one thread per output element.
__global__ __launch_bounds__(256)
void reduce_kernel(const float* __restrict__ opart, const float* __restrict__ ml,
                   float* __restrict__ out) {
    const int e   = blockIdx.x * 256 + threadIdx.x;
    const int col = e & 63;
    const int row = e >> 6;                 // global row = b*SEQ + sq
    const int b   = row >> 12;
    const int sq  = row & (SEQ - 1);
    const int t   = sq >> 6;
    const int gi  = (63 - t) * 4 + b;
    const int r64 = sq & 63;
    const int nkb = (t + 1) * 64;
    const int chunk = ((nkb + 511) >> 9) << 6;
    const int nsp   = (nkb + chunk - 1) / chunk;

    float M = -INFINITY, ls = 0.f, o = 0.f;
    for (int sp = 0; sp < nsp; ++sp) {
        const size_t base = (size_t)gi * KSPLIT + sp;
        const float lv = ml[base * 128 + 64 + r64];
        if (lv > 0.f) {
            const float mv = ml[base * 128 + r64];
            const float nm = fmaxf(M, mv);
            const float f0 = __builtin_exp2f(M - nm);   // M=-inf first -> 0
            const float f1 = __builtin_exp2f(mv - nm);
            const float ov = opart[base * (64 * 64) + (size_t)r64 * 64 + col];
            o  = o * f0 + f1 * ov;
            ls = ls * f0 + f1 * lv;
            M = nm;
        }
    }
    out[e] = o / ls;
}

extern "C" void kernel_launch(void* const* d_in, const int* in_sizes, int n_in,
                              void* d_out, int out_size, void* d_ws, size_t ws_size,
                              hipStream_t stream) {
    const float* hidden = (const float*)d_in[0];
    const float* Wq = (const float*)d_in[1];
    const float* bq = (const float*)d_in[2];
    const float* Wk = (const float*)d_in[3];
    const float* bk = (const float*)d_in[4];
    const float* Wv = (const float*)d_in[5];
    const float* bv = (const float*)d_in[6];

    __bf16* qbuf  = (__bf16*)d_ws;                     // [NROW][64] (pre-scaled)
    __bf16* kbuf  = qbuf + (size_t)NROW * HD;          // [NROW][64]
    __bf16* vtbuf = kbuf + (size_t)NROW * HD;          // [64][NROW] (V transposed)
    __bf16* wT    = vtbuf + (size_t)NROW * HD;         // [192][768]
    float*  opart = (float*)(wT + (size_t)192 * EMBED);        // [NBAND*KSPLIT][64][64]
    float*  ml    = opart + (size_t)NBAND * KSPLIT * 64 * 64;  // [NBAND*KSPLIT][128]

    wconv_kernel<<<(192 * EMBED) / 256, 256, 0, stream>>>(Wq, Wk, Wv, wT);

    qkv_gemm_kernel<<<NROW / 16, 256, 0, stream>>>(
        hidden, wT, bq, bk, bv, qbuf, kbuf, vtbuf);

    attn_kernel<<<NBAND * KSPLIT, 256, 0, stream>>>(
        qbuf, kbuf, vtbuf, opart, ml);

    reduce_kernel<<<(NROW * HD) / 256, 256, 0, stream>>>(opart, ml, (float*)d_out);
}

// Round 10
// 232.677 us; speedup vs baseline: 1.1356x; 1.1356x over previous
//
#include <hip/hip_runtime.h>
#include <stdint.h>

#define EMBED 768
#define HD 64
#define SEQ 4096
#define BATCH 4
#define NROW (BATCH * SEQ)   // 16384
#define NBAND (NROW / 64)    // 256 bands of 64 query rows
#define KSPLIT 8

typedef __bf16 bf16x8 __attribute__((ext_vector_type(8)));
typedef __bf16 bf16x4 __attribute__((ext_vector_type(4)));
typedef float f32x4 __attribute__((ext_vector_type(4)));

// ---------------- W -> wT [192][768] bf16 (once, tiny) ----------------
__global__ __launch_bounds__(256)
void wconv_kernel(const float* __restrict__ Wq, const float* __restrict__ Wk,
                  const float* __restrict__ Wv, __bf16* __restrict__ wT) {
    int id = blockIdx.x * 256 + threadIdx.x;   // < 192*768
    int c = id / EMBED, k = id - c * EMBED;
    const float* W = (c < 64) ? Wq : (c < 128) ? Wk : Wv;
    wT[id] = (__bf16)W[(size_t)k * HD + (c & 63)];
}

// ---------------- fused QKV GEMM (UNCHANGED from R8/R9 for attribution) ----------------
__global__ __launch_bounds__(256, 4)
void qkv_gemm_kernel(const float* __restrict__ hidden, const __bf16* __restrict__ wT,
                     const float* __restrict__ bq, const float* __restrict__ bk,
                     const float* __restrict__ bv,
                     __bf16* __restrict__ qo, __bf16* __restrict__ ko,
                     __bf16* __restrict__ vto) {
    const int m0 = blockIdx.x * 16;
    const int w  = threadIdx.x >> 6;
    const int lane = threadIdx.x & 63, lr = lane & 15, lg = lane >> 4;

    f32x4 acc[3];
    #pragma unroll
    for (int j = 0; j < 3; ++j) acc[j] = (f32x4){0.f, 0.f, 0.f, 0.f};

    const float* hrow = hidden + (size_t)(m0 + lr) * EMBED + lg * 8;

    float4 c00 = *(const float4*)(hrow + 0);
    float4 c01 = *(const float4*)(hrow + 4);
    float4 c10 = *(const float4*)(hrow + 32);
    float4 c11 = *(const float4*)(hrow + 36);

    for (int k0 = 0; k0 < EMBED; k0 += 64) {
        const float* pf = hrow + ((k0 + 64 < EMBED) ? (k0 + 64) : k0);
        float4 n00 = *(const float4*)(pf + 0);
        float4 n01 = *(const float4*)(pf + 4);
        float4 n10 = *(const float4*)(pf + 32);
        float4 n11 = *(const float4*)(pf + 36);

        bf16x8 a0, a1;
        a0[0] = (__bf16)c00.x; a0[1] = (__bf16)c00.y; a0[2] = (__bf16)c00.z; a0[3] = (__bf16)c00.w;
        a0[4] = (__bf16)c01.x; a0[5] = (__bf16)c01.y; a0[6] = (__bf16)c01.z; a0[7] = (__bf16)c01.w;
        a1[0] = (__bf16)c10.x; a1[1] = (__bf16)c10.y; a1[2] = (__bf16)c10.z; a1[3] = (__bf16)c10.w;
        a1[4] = (__bf16)c11.x; a1[5] = (__bf16)c11.y; a1[6] = (__bf16)c11.z; a1[7] = (__bf16)c11.w;

        #pragma unroll
        for (int j = 0; j < 3; ++j) {
            const int col = w * 48 + j * 16 + lr;       // 0..191
            bf16x8 b0 = *(const bf16x8*)(wT + (size_t)col * EMBED + k0 + lg * 8);
            acc[j] = __builtin_amdgcn_mfma_f32_16x16x32_bf16(a0, b0, acc[j], 0, 0, 0);
            bf16x8 b1 = *(const bf16x8*)(wT + (size_t)col * EMBED + k0 + 32 + lg * 8);
            acc[j] = __builtin_amdgcn_mfma_f32_16x16x32_bf16(a1, b1, acc[j], 0, 0, 0);
        }
        c00 = n00; c01 = n01; c10 = n10; c11 = n11;
    }

    const float qsc = 0.18033688011112042f;   // log2(e)/sqrt(64)
    const int row0 = m0 + lg * 4;             // C/D: row=(lane>>4)*4+r, col=lr
    #pragma unroll
    for (int j = 0; j < 3; ++j) {
        const int cw  = w * 48 + j * 16;      // 16-col group lies in ONE matrix
        const int mat = cw >> 6;
        const int cm  = (cw & 63) + lr;
        if (mat == 0) {
            const float bb = bq[cm];
            #pragma unroll
            for (int r = 0; r < 4; ++r)
                qo[(size_t)(row0 + r) * HD + cm] = (__bf16)((acc[j][r] + bb) * qsc);
        } else if (mat == 1) {
            const float bb = bk[cm];
            #pragma unroll
            for (int r = 0; r < 4; ++r)
                ko[(size_t)(row0 + r) * HD + cm] = (__bf16)(acc[j][r] + bb);
        } else {
            const float bb = bv[cm];
            bf16x4 pv;
            pv[0] = (__bf16)(acc[j][0] + bb);
            pv[1] = (__bf16)(acc[j][1] + bb);
            pv[2] = (__bf16)(acc[j][2] + bb);
            pv[3] = (__bf16)(acc[j][3] + bb);
            *(bf16x4*)&vto[(size_t)cm * NROW + row0] = pv;   // V transposed
        }
    }
}

// ---------------- causal flash attention ----------------
// R4 band geometry + KBLK=32 register diet: live state ~60 VGPR fits the
// 64-VGPR step honestly -> (256,8) gives 8 waves/SIMD with NO spill.
// grid: NBAND*KSPLIT = 2048 blocks x 256 thr (4 waves). Block = 64-row band x
// one key split; all 4 waves iterate the SAME keys (L1/L2-shared).
__global__ __launch_bounds__(256, 8)
void attn_kernel(const __bf16* __restrict__ qg, const __bf16* __restrict__ kg,
                 const __bf16* __restrict__ vtg,
                 float* __restrict__ opart, float* __restrict__ ml) {
    __shared__ __bf16 p_lds[4][16][40];   // per-wave P (16x32); 80B stride: 2-way banks

    const int bid = blockIdx.x;
    const int gi  = bid >> 3;            // band index (descending work)
    const int sp  = bid & (KSPLIT - 1);
    const int t   = 63 - (gi >> 2);      // per-batch 64-row band, longest first
    const int b   = gi & 3;
    const int q0b = t * 64;
    const int nkb = q0b + 64;
    const int chunk = ((nkb + KSPLIT * 32 - 1) / (KSPLIT * 32)) * 32;  // KBLK-aligned
    const int kb = sp * chunk;

    const int w    = threadIdx.x >> 6;
    const int lane = threadIdx.x & 63, lr = lane & 15, lg = lane >> 4;
    const int q0 = q0b + w * 16;         // wave's 16 rows
    const int nk = q0 + 16;
    const int ke = (kb + chunk < nk) ? (kb + chunk) : nk;

    float* mlp = ml + ((size_t)gi * KSPLIT + sp) * 128;   // [0..64)=m, [64..128)=l
    const int rb = w * 16 + lg * 4;      // row-in-band base for this thread

    if (kb >= ke) {                      // empty split for this wave: l=0
        if (lr == 0) {
            #pragma unroll
            for (int r = 0; r < 4; ++r) mlp[64 + rb + r] = 0.f;
        }
        return;
    }

    const __bf16* qb = qg  + (size_t)b * SEQ * HD;
    const __bf16* kp = kg  + (size_t)b * SEQ * HD;
    const __bf16* vb = vtg + (size_t)b * SEQ;   // vb[d*NROW + key]

    const bf16x8 qf0 = *(const bf16x8*)&qb[(q0 + lr) * HD + lg * 8];
    const bf16x8 qf1 = *(const bf16x8*)&qb[(q0 + lr) * HD + 32 + lg * 8];

    f32x4 acc[4];
    const f32x4 zero4 = {0.f, 0.f, 0.f, 0.f};
    #pragma unroll
    for (int n = 0; n < 4; ++n) acc[n] = zero4;
    float m[4], lsum[4];
    #pragma unroll
    for (int r = 0; r < 4; ++r) { m[r] = -INFINITY; lsum[r] = 0.f; }

    for (int kb0 = kb; kb0 < ke; kb0 += 32) {
        f32x4 sj[2];   // scores in exp2 domain (Q pre-scaled); KBLK=32
        #pragma unroll
        for (int j = 0; j < 2; ++j) {
            bf16x8 kf0 = *(const bf16x8*)&kp[(size_t)(kb0 + j * 16 + lr) * HD + lg * 8];
            bf16x8 kf1 = *(const bf16x8*)&kp[(size_t)(kb0 + j * 16 + lr) * HD + 32 + lg * 8];
            f32x4 z = zero4;
            z = __builtin_amdgcn_mfma_f32_16x16x32_bf16(qf0, kf0, z, 0, 0, 0);
            z = __builtin_amdgcn_mfma_f32_16x16x32_bf16(qf1, kf1, z, 0, 0, 0);
            sj[j] = z;
        }

        if (kb0 + 31 > q0) {  // tile crosses this wave's diagonal: causal mask
            #pragma unroll
            for (int j = 0; j < 2; ++j)
                #pragma unroll
                for (int r = 0; r < 4; ++r)
                    if (kb0 + j * 16 + lr > q0 + lg * 4 + r) sj[j][r] = -1e30f;
        }

        float mx[4];
        #pragma unroll
        for (int r = 0; r < 4; ++r) mx[r] = fmaxf(sj[0][r], sj[1][r]);
        #pragma unroll
        for (int off = 1; off < 16; off <<= 1)
            #pragma unroll
            for (int r = 0; r < 4; ++r) mx[r] = fmaxf(mx[r], __shfl_xor(mx[r], off));

        float rs[4], so[4];
        #pragma unroll
        for (int r = 0; r < 4; ++r) {
            const float nm = fmaxf(m[r], mx[r]);
            so[r] = __builtin_exp2f(m[r] - nm);   // m=-inf first iter -> 0
            m[r] = nm;
            sj[0][r] = __builtin_exp2f(sj[0][r] - nm);   // P in place
            sj[1][r] = __builtin_exp2f(sj[1][r] - nm);
            rs[r] = sj[0][r] + sj[1][r];
        }
        #pragma unroll
        for (int off = 1; off < 16; off <<= 1)
            #pragma unroll
            for (int r = 0; r < 4; ++r) rs[r] += __shfl_xor(rs[r], off);
        #pragma unroll
        for (int r = 0; r < 4; ++r) lsum[r] = lsum[r] * so[r] + rs[r];
        #pragma unroll
        for (int n = 0; n < 4; ++n)
            #pragma unroll
            for (int r = 0; r < 4; ++r) acc[n][r] *= so[r];

        // P (16x32) -> per-wave LDS bf16, re-read as A-fragment (fence only)
        #pragma unroll
        for (int j = 0; j < 2; ++j)
            #pragma unroll
            for (int r = 0; r < 4; ++r)
                p_lds[w][lg * 4 + r][j * 16 + lr] = (__bf16)sj[j][r];
        asm volatile("s_waitcnt lgkmcnt(0)" ::: "memory");
        const bf16x8 pa = *(const bf16x8*)&p_lds[w][lr][lg * 8];
        #pragma unroll
        for (int n = 0; n < 4; ++n) {
            bf16x8 vf = *(const bf16x8*)&vb[(size_t)(n * 16 + lr) * NROW + kb0 + lg * 8];
            acc[n] = __builtin_amdgcn_mfma_f32_16x16x32_bf16(pa, vf, acc[n], 0, 0, 0);
        }
        asm volatile("" ::: "memory");
    }

    // epilogue: unnormalized O partial + per-row m/l
    float* Op = opart + (size_t)(gi * KSPLIT + sp) * (64 * 64);
    #pragma unroll
    for (int n = 0; n < 4; ++n)
        #pragma unroll
        for (int r = 0; r < 4; ++r)
            Op[(size_t)(rb + r) * 64 + n * 16 + lr] = acc[n][r];
    if (lr == 0) {
        #pragma unroll
        for (int r = 0; r < 4; ++r) {
            mlp[rb + r]      = m[r];
            mlp[64 + rb + r] = (m[r] > -1e29f) ? lsum[r] : 0.f;
        }
    }
}

// ---------------- combine split-K partials ----------------
// grid: NROW*HD/256 x 256 thr; one thread per output element.
__global__ __launch_bounds__(256)
void reduce_kernel(const float* __restrict__ opart, const float* __restrict__ ml,
                   float* __restrict__ out) {
    const int e   = blockIdx.x * 256 + threadIdx.x;
    const int col = e & 63;
    const int row = e >> 6;                 // global row = b*SEQ + sq
    const int b   = row >> 12;
    const int sq  = row & (SEQ - 1);
    const int t   = sq >> 6;
    const int gi  = (63 - t) * 4 + b;
    const int r64 = sq & 63;
    const int nkb = (t + 1) * 64;
    const int chunk = ((nkb + KSPLIT * 32 - 1) / (KSPLIT * 32)) * 32;  // match attn
    const int nsp   = (nkb + chunk - 1) / chunk;

    float M = -INFINITY, ls = 0.f, o = 0.f;
    for (int sp = 0; sp < nsp; ++sp) {
        const size_t base = (size_t)gi * KSPLIT + sp;
        const float lv = ml[base * 128 + 64 + r64];
        if (lv > 0.f) {
            const float mv = ml[base * 128 + r64];
            const float nm = fmaxf(M, mv);
            const float f0 = __builtin_exp2f(M - nm);   // M=-inf first -> 0
            const float f1 = __builtin_exp2f(mv - nm);
            const float ov = opart[base * (64 * 64) + (size_t)r64 * 64 + col];
            o  = o * f0 + f1 * ov;
            ls = ls * f0 + f1 * lv;
            M = nm;
        }
    }
    out[e] = o / ls;
}

extern "C" void kernel_launch(void* const* d_in, const int* in_sizes, int n_in,
                              void* d_out, int out_size, void* d_ws, size_t ws_size,
                              hipStream_t stream) {
    const float* hidden = (const float*)d_in[0];
    const float* Wq = (const float*)d_in[1];
    const float* bq = (const float*)d_in[2];
    const float* Wk = (const float*)d_in[3];
    const float* bk = (const float*)d_in[4];
    const float* Wv = (const float*)d_in[5];
    const float* bv = (const float*)d_in[6];

    __bf16* qbuf  = (__bf16*)d_ws;                     // [NROW][64] (pre-scaled)
    __bf16* kbuf  = qbuf + (size_t)NROW * HD;          // [NROW][64]
    __bf16* vtbuf = kbuf + (size_t)NROW * HD;          // [64][NROW] (V transposed)
    __bf16* wT    = vtbuf + (size_t)NROW * HD;         // [192][768]
    float*  opart = (float*)(wT + (size_t)192 * EMBED);        // [NBAND*KSPLIT][64][64]
    float*  ml    = opart + (size_t)NBAND * KSPLIT * 64 * 64;  // [NBAND*KSPLIT][128]

    wconv_kernel<<<(192 * EMBED) / 256, 256, 0, stream>>>(Wq, Wk, Wv, wT);

    qkv_gemm_kernel<<<NROW / 16, 256, 0, stream>>>(
        hidden, wT, bq, bk, bv, qbuf, kbuf, vtbuf);

    attn_kernel<<<NBAND * KSPLIT, 256, 0, stream>>>(
        qbuf, kbuf, vtbuf, opart, ml);

    reduce_kernel<<<(NROW * HD) / 256, 256, 0, stream>>>(opart, ml, (float*)d_out);
}